// Round 1
// baseline (407.629 us; speedup 1.0000x reference)
//
#include <hip/hip_runtime.h>

// Problem constants (fixed shape)
// N=8192 tokens, D=1280, H=16 heads, K=80 head dim (pad 96), S=16 segs, L=512
#define LOG2E 1.44269504088896340736f
#define ATT_SCALE 0.11180339887498949f  // 80^-0.5

typedef _Float16 half8 __attribute__((ext_vector_type(8)));
typedef _Float16 half4v __attribute__((ext_vector_type(4)));
typedef float f32x4 __attribute__((ext_vector_type(4)));

#define MFMA(a, b, c) __builtin_amdgcn_mfma_f32_16x16x32_f16((a), (b), (c), 0, 0, 0)

// async global->LDS DMA, 16B per lane; lds ptr must be wave-uniform chunk base,
// HW writes lane i at base + i*16.
__device__ __forceinline__ void async16(const _Float16* g, _Float16* l) {
  __builtin_amdgcn_global_load_lds(
      (const __attribute__((address_space(1))) unsigned int*)g,
      (__attribute__((address_space(3))) unsigned int*)l,
      16, 0, 0);
}

// ---------------- fp32 -> fp16 convert (hidden) ----------------
__global__ __launch_bounds__(256) void cvt_k(const float* __restrict__ in,
                                             _Float16* __restrict__ out, int n4) {
  int i = blockIdx.x * 256 + threadIdx.x;
  if (i < n4) {
    f32x4 v = ((const f32x4*)in)[i];
    half4v hv;
    hv[0] = (_Float16)v[0]; hv[1] = (_Float16)v[1];
    hv[2] = (_Float16)v[2]; hv[3] = (_Float16)v[3];
    ((half4v*)out)[i] = hv;
  }
}

// ---------------- transpose + convert: in R x C fp32 -> out C x R fp16 ----------
__global__ __launch_bounds__(256) void transpose_cvt_k(const float* __restrict__ in,
                                                       _Float16* __restrict__ out,
                                                       int R, int C) {
  __shared__ float tile[32][33];
  const int tx = threadIdx.x & 31, ty = threadIdx.x >> 5;
  const int c0 = blockIdx.x * 32, r0 = blockIdx.y * 32;
#pragma unroll
  for (int i = 0; i < 32; i += 8)
    tile[ty + i][tx] = in[(size_t)(r0 + ty + i) * C + c0 + tx];
  __syncthreads();
#pragma unroll
  for (int i = 0; i < 32; i += 8)
    out[(size_t)(c0 + ty + i) * R + r0 + tx] = (_Float16)tile[tx][ty + i];
}

// ---------------- GEMM (m97 structure): C = A(8192xKd) * BT^T, Kd=1280 --------
// MODE 0: N=3840, scatter epilogue -> Qf/Kf (seg-head x 512 x 96) and VTf (seg-head x 80 x 512)
// MODE 1: N=1280, Out fp32 = val + bias
template <int MODE>
__global__ __launch_bounds__(256) void gemm_k(const _Float16* __restrict__ A,
                                              const _Float16* __restrict__ BT,
                                              const float* __restrict__ bias,
                                              _Float16* __restrict__ Qf,
                                              _Float16* __restrict__ Kf,
                                              _Float16* __restrict__ VTf,
                                              float* __restrict__ Out) {
  __shared__ _Float16 sA[128 * 32];
  __shared__ _Float16 sB[128 * 32];
  const int tid = threadIdx.x;
  const int wave = tid >> 6, lane = tid & 63;
  const int quad = lane >> 4, l16 = lane & 15;
  const int m0 = blockIdx.x * 128;
  const int n0 = blockIdx.y * 128;
  const int mw = (wave & 1) * 64, nw = (wave >> 1) * 64;
  const int KD = 1280;

  f32x4 acc[4][4] = {};

  for (int kt = 0; kt < KD; kt += 32) {
    // stage A,B tiles (128x32 fp16 each = 8KB each, 8 chunks of 1KB)
#pragma unroll
    for (int c = 0; c < 2; ++c) {
      const int j = wave * 2 + c;
      const int row = j * 16 + (lane >> 2);
      const int colh = (lane & 3) * 8;
      async16(A + (size_t)(m0 + row) * KD + kt + colh, &sA[j * 512]);
      async16(BT + (size_t)(n0 + row) * KD + kt + colh, &sB[j * 512]);
    }
    __syncthreads();
    half8 af[4], bf[4];
#pragma unroll
    for (int i = 0; i < 4; ++i) {
      af[i] = *(const half8*)&sA[(mw + i * 16 + l16) * 32 + quad * 8];
      bf[i] = *(const half8*)&sB[(nw + i * 16 + l16) * 32 + quad * 8];
    }
#pragma unroll
    for (int i = 0; i < 4; ++i)
#pragma unroll
      for (int j2 = 0; j2 < 4; ++j2)
        acc[i][j2] = MFMA(af[i], bf[j2], acc[i][j2]);
    __syncthreads();
  }

  // epilogue: C row = (quad*4+reg), col = l16  [m89-verified]
#pragma unroll
  for (int i = 0; i < 4; ++i) {
#pragma unroll
    for (int j2 = 0; j2 < 4; ++j2) {
      const int col = n0 + nw + j2 * 16 + l16;
      const float bv = bias[col];
      const int rowb = m0 + mw + i * 16 + quad * 4;
#pragma unroll
      for (int r = 0; r < 4; ++r) {
        const float v = acc[i][j2][r] + bv;
        const int mrow = rowb + r;
        if (MODE == 0) {
          const int which = col / 1280;
          const int rem = col - which * 1280;
          const int h = rem / 80;
          const int kk = rem - h * 80;
          const int s = mrow >> 9, l = mrow & 511;
          const int shh = s * 16 + h;
          if (which == 0)
            Qf[((size_t)shh * 512 + l) * 96 + kk] = (_Float16)v;
          else if (which == 1)
            Kf[((size_t)shh * 512 + l) * 96 + kk] = (_Float16)v;
          else
            VTf[((size_t)shh * 80 + kk) * 512 + l] = (_Float16)v;
        } else {
          Out[(size_t)mrow * 1280 + col] = v;
        }
      }
    }
  }
}

// ---------------- RoPE in-place on Qf/Kf + zero the k-pad [80,96) -------------
// one 64-lane wave per (buffer,row); lane j<40 handles the pair (j, j+40)
__global__ __launch_bounds__(256) void rope_k(_Float16* __restrict__ Qf,
                                              _Float16* __restrict__ Kf,
                                              const float* __restrict__ cosNK,
                                              const float* __restrict__ sinNK) {
  const int gid = blockIdx.x * 256 + threadIdx.x;
  const int j = gid & 63;
  const int row = gid >> 6;        // 0 .. 2*131072-1
  const int qk = row >> 17;
  const int r = row & 131071;      // (s*16+h)*512 + l
  _Float16* buf = qk ? Kf : Qf;
  const int l = r & 511;
  const int s = r >> 13;
  const int t = s * 512 + l;
  const size_t base = (size_t)r * 96;
  if (j < 40) {
    const float v1 = (float)buf[base + j];
    const float v2 = (float)buf[base + j + 40];
    const float c1 = cosNK[t * 80 + j], s1 = sinNK[t * 80 + j];
    const float c2 = cosNK[t * 80 + j + 40], s2 = sinNK[t * 80 + j + 40];
    buf[base + j] = (_Float16)(v1 * c1 - v2 * s1);
    buf[base + j + 40] = (_Float16)(v2 * c2 + v1 * s2);
  } else if (j < 56) {
    buf[base + 40 + j] = (_Float16)0.f;  // kk = 80..95
  }
}

// ---------------- flash attention: block = (seg-head, 128-row q tile) ---------
// BR=128, BC=64, head dim 80 padded to 96. Online softmax in fp32.
__global__ __launch_bounds__(256) void attn_k(const _Float16* __restrict__ Qf,
                                              const _Float16* __restrict__ Kf,
                                              const _Float16* __restrict__ VTf,
                                              _Float16* __restrict__ attnA) {
  // sQP: Q tile 128x96 (12288 h) aliased with P tile 128 x stride72 (9216 h)
  __shared__ _Float16 sQP[128 * 96];
  __shared__ _Float16 sK[64 * 96];       // 6144 h
  __shared__ _Float16 sV[12 * 512];      // VT tile, 80 rows x stride 72 (padded)
  const int tid = threadIdx.x;
  const int wave = tid >> 6, lane = tid & 63;
  const int quad = lane >> 4, l16 = lane & 15;
  const int shh = blockIdx.x;  // s*16+h
  const int qt = blockIdx.y;   // 0..3
  const int h = shh & 15;
  const int s = shh >> 4;

  const _Float16* Qb = Qf + ((size_t)shh * 512 + qt * 128) * 96;
  const _Float16* Kb0 = Kf + (size_t)shh * 512 * 96;
  const _Float16* Vb0 = VTf + (size_t)shh * 80 * 512;

  // stage Q (contiguous 24KB = 24 chunks)
#pragma unroll
  for (int c = 0; c < 6; ++c) {
    const int j = wave + 4 * c;
    async16(Qb + j * 512 + lane * 8, &sQP[j * 512]);
  }
  __syncthreads();
  // hoist Q A-frags: wave owns q-rows [wave*32, wave*32+32)
  half8 qf[2][3];
#pragma unroll
  for (int rt = 0; rt < 2; ++rt)
#pragma unroll
    for (int ks = 0; ks < 3; ++ks)
      qf[rt][ks] = *(const half8*)&sQP[(wave * 32 + rt * 16 + l16) * 96 + ks * 32 + quad * 8];

  f32x4 o[2][5] = {};
  float mrow[2][4], lrow[2][4];
#pragma unroll
  for (int rt = 0; rt < 2; ++rt)
#pragma unroll
    for (int r = 0; r < 4; ++r) { mrow[rt][r] = -1e30f; lrow[rt][r] = 0.f; }

  const float C1 = ATT_SCALE * LOG2E;

  for (int kc = 0; kc < 8; ++kc) {
    __syncthreads();  // prev iter LDS reads done (and Q hoist done on iter 0)
    // stage K tile: 64x96 contiguous (12 chunks)
    const _Float16* Kb = Kb0 + (size_t)kc * 64 * 96;
#pragma unroll
    for (int c = 0; c < 3; ++c) {
      const int j = wave + 4 * c;
      async16(Kb + j * 512 + lane * 8, &sK[j * 512]);
    }
    // stage VT tile into padded layout (row stride 72 halves = 144B), masked DMA
#pragma unroll
    for (int c = 0; c < 3; ++c) {
      const int j = wave + 4 * c;
      const int off = j * 1024 + lane * 16;  // LDS byte offset
      const int vrow = off / 144;            // feature 0..79 (pad rows masked)
      const int colb = off - vrow * 144;     // byte within padded row
      if (vrow < 80 && colb < 128)
        async16(Vb0 + (size_t)vrow * 512 + kc * 64 + (colb >> 1), &sV[j * 512]);
    }
    __syncthreads();

    // S = Q K^T  (raw logits, fp32 acc)
    f32x4 sacc[2][4] = {};
#pragma unroll
    for (int nt = 0; nt < 4; ++nt) {
#pragma unroll
      for (int ks = 0; ks < 3; ++ks) {
        half8 kb = *(const half8*)&sK[(nt * 16 + l16) * 96 + ks * 32 + quad * 8];
        sacc[0][nt] = MFMA(qf[0][ks], kb, sacc[0][nt]);
        sacc[1][nt] = MFMA(qf[1][ks], kb, sacc[1][nt]);
      }
    }

    // online softmax (base-2 domain: x = raw*SCALE*log2e)
#pragma unroll
    for (int rt = 0; rt < 2; ++rt) {
#pragma unroll
      for (int r = 0; r < 4; ++r) {
        float mx = -1e30f;
#pragma unroll
        for (int nt = 0; nt < 4; ++nt) mx = fmaxf(mx, sacc[rt][nt][r]);
#pragma unroll
        for (int off = 1; off < 16; off <<= 1) mx = fmaxf(mx, __shfl_xor(mx, off));
        const float mnew = fmaxf(mrow[rt][r], mx * C1);
        const float alpha = exp2f(mrow[rt][r] - mnew);
        mrow[rt][r] = mnew;
        float rs = 0.f;
#pragma unroll
        for (int nt = 0; nt < 4; ++nt) {
          const float p = exp2f(sacc[rt][nt][r] * C1 - mnew);
          sacc[rt][nt][r] = p;
          rs += p;
        }
#pragma unroll
        for (int off = 1; off < 16; off <<= 1) rs += __shfl_xor(rs, off);
        lrow[rt][r] = lrow[rt][r] * alpha + rs;
#pragma unroll
        for (int ft = 0; ft < 5; ++ft) o[rt][ft][r] *= alpha;
      }
    }

    // P -> LDS (C-layout -> A-layout round trip), stride 72 kills bank conflicts
    _Float16* sP = sQP;
#pragma unroll
    for (int rt = 0; rt < 2; ++rt)
#pragma unroll
      for (int nt = 0; nt < 4; ++nt)
#pragma unroll
        for (int r = 0; r < 4; ++r)
          sP[(wave * 32 + rt * 16 + quad * 4 + r) * 72 + nt * 16 + l16] =
              (_Float16)sacc[rt][nt][r];
    __syncthreads();

    // O += P V
#pragma unroll
    for (int ks = 0; ks < 2; ++ks) {
      half8 pa[2];
      pa[0] = *(const half8*)&sP[(wave * 32 + 0 + l16) * 72 + ks * 32 + quad * 8];
      pa[1] = *(const half8*)&sP[(wave * 32 + 16 + l16) * 72 + ks * 32 + quad * 8];
#pragma unroll
      for (int ft = 0; ft < 5; ++ft) {
        half8 vb = *(const half8*)&sV[(ft * 16 + l16) * 72 + ks * 32 + quad * 8];
        o[0][ft] = MFMA(pa[0], vb, o[0][ft]);
        o[1][ft] = MFMA(pa[1], vb, o[1][ft]);
      }
    }
  }

  // epilogue: divide by l, store fp16 into attnA [token][h*80+f]
#pragma unroll
  for (int rt = 0; rt < 2; ++rt) {
#pragma unroll
    for (int r = 0; r < 4; ++r) {
      const float inv = 1.0f / lrow[rt][r];
      const int token = s * 512 + qt * 128 + wave * 32 + rt * 16 + quad * 4 + r;
#pragma unroll
      for (int ft = 0; ft < 5; ++ft)
        attnA[(size_t)token * 1280 + h * 80 + ft * 16 + l16] =
            (_Float16)(o[rt][ft][r] * inv);
    }
  }
}

extern "C" void kernel_launch(void* const* d_in, const int* in_sizes, int n_in,
                              void* d_out, int out_size, void* d_ws, size_t ws_size,
                              hipStream_t stream) {
  (void)in_sizes; (void)n_in; (void)out_size; (void)ws_size;
  const float* hidden = (const float*)d_in[0];
  // d_in[1] = cu_seqlens (equal 512-token segments; reference ignores values)
  const float* cosNK = (const float*)d_in[2];
  const float* sinNK = (const float*)d_in[3];
  const float* qkv_w = (const float*)d_in[4];
  const float* qkv_b = (const float*)d_in[5];
  const float* proj_w = (const float*)d_in[6];
  const float* proj_b = (const float*)d_in[7];
  float* out = (float*)d_out;

  char* ws = (char*)d_ws;
  _Float16* hA    = (_Float16*)(ws);                   // 8192x1280        20971520 B
  _Float16* wT    = (_Float16*)(ws + 20971520);        // 3840x1280         9830400 B
  _Float16* projT = (_Float16*)(ws + 30801920);        // 1280x1280         3276800 B
  _Float16* Qf    = (_Float16*)(ws + 34078720);        // 256x512x96       25165824 B
  _Float16* Kf    = (_Float16*)(ws + 59244544);        // 256x512x96       25165824 B
  _Float16* VTf   = (_Float16*)(ws + 84410368);        // 256x80x512       20971520 B
  _Float16* attnA = (_Float16*)(ws + 105381888);       // 8192x1280        20971520 B
  // total ws needed: 126353408 B

  cvt_k<<<10240, 256, 0, stream>>>(hidden, hA, 2621440);
  transpose_cvt_k<<<dim3(120, 40), 256, 0, stream>>>(qkv_w, wT, 1280, 3840);
  transpose_cvt_k<<<dim3(40, 40), 256, 0, stream>>>(proj_w, projT, 1280, 1280);
  gemm_k<0><<<dim3(64, 30), 256, 0, stream>>>(hA, wT, qkv_b, Qf, Kf, VTf, nullptr);
  rope_k<<<65536, 256, 0, stream>>>(Qf, Kf, cosNK, sinNK);
  attn_k<<<dim3(256, 4), 256, 0, stream>>>(Qf, Kf, VTf, attnA);
  gemm_k<1><<<dim3(64, 10), 256, 0, stream>>>(attnA, projT, proj_b, nullptr, nullptr,
                                              nullptr, out);
}

// Round 2
// 389.864 us; speedup vs baseline: 1.0456x; 1.0456x over previous
//
#include <hip/hip_runtime.h>

// Problem constants (fixed shape)
// N=8192 tokens, D=1280, H=16 heads, K=80 head dim (pad 96), S=16 segs, L=512
#define LOG2E 1.44269504088896340736f
#define ATT_SCALE 0.11180339887498949f  // 80^-0.5

typedef _Float16 half8 __attribute__((ext_vector_type(8)));
typedef _Float16 half4v __attribute__((ext_vector_type(4)));
typedef float f32x4 __attribute__((ext_vector_type(4)));

#define MFMA(a, b, c) __builtin_amdgcn_mfma_f32_16x16x32_f16((a), (b), (c), 0, 0, 0)

__device__ __forceinline__ void async16(const _Float16* g, _Float16* l) {
  __builtin_amdgcn_global_load_lds(
      (const __attribute__((address_space(1))) unsigned int*)g,
      (__attribute__((address_space(3))) unsigned int*)l,
      16, 0, 0);
}

// ---------------- fp32 -> fp16 convert (hidden) ----------------
__global__ __launch_bounds__(256) void cvt_k(const float* __restrict__ in,
                                             _Float16* __restrict__ out, int n4) {
  int i = blockIdx.x * 256 + threadIdx.x;
  if (i < n4) {
    f32x4 v = ((const f32x4*)in)[i];
    half4v hv;
    hv[0] = (_Float16)v[0]; hv[1] = (_Float16)v[1];
    hv[2] = (_Float16)v[2]; hv[3] = (_Float16)v[3];
    ((half4v*)out)[i] = hv;
  }
}

// ---------------- transpose + convert: in R x C fp32 -> out C x R fp16 ----------
__global__ __launch_bounds__(256) void transpose_cvt_k(const float* __restrict__ in,
                                                       _Float16* __restrict__ out,
                                                       int R, int C) {
  __shared__ float tile[32][33];
  const int tx = threadIdx.x & 31, ty = threadIdx.x >> 5;
  const int c0 = blockIdx.x * 32, r0 = blockIdx.y * 32;
#pragma unroll
  for (int i = 0; i < 32; i += 8)
    tile[ty + i][tx] = in[(size_t)(r0 + ty + i) * C + c0 + tx];
  __syncthreads();
#pragma unroll
  for (int i = 0; i < 32; i += 8)
    out[(size_t)(c0 + ty + i) * R + r0 + tx] = (_Float16)tile[tx][ty + i];
}

// ---------------- GEMM: C = A(8192xKd) * BT^T, Kd=1280, BK=64, XOR swizzle ----
// LDS layout: row stride 64 halves; col-group (8 halves) physical = logical ^ (row&7)
// MODE 0: N=3840, scatter epilogue -> Qf/Kf (seg-head x 512 x 96) and VTf (80 x 512)
// MODE 1: N=1280, Out fp32 = val + bias
template <int MODE>
__global__ __launch_bounds__(256) void gemm_k(const _Float16* __restrict__ A,
                                              const _Float16* __restrict__ BT,
                                              const float* __restrict__ bias,
                                              _Float16* __restrict__ Qf,
                                              _Float16* __restrict__ Kf,
                                              _Float16* __restrict__ VTf,
                                              float* __restrict__ Out) {
  __shared__ _Float16 sA[128 * 64];
  __shared__ _Float16 sB[128 * 64];
  const int tid = threadIdx.x;
  const int wave = tid >> 6, lane = tid & 63;
  const int quad = lane >> 4, l16 = lane & 15;
  const int m0 = blockIdx.x * 128;
  const int n0 = blockIdx.y * 128;
  const int mw = (wave & 1) * 64, nw = (wave >> 1) * 64;
  const int KD = 1280;

  f32x4 acc[4][4] = {};

  for (int kt = 0; kt < KD; kt += 64) {
    // stage A,B 128x64 tiles (16 KB each, 16 chunks of 1KB; wave stages 4)
#pragma unroll
    for (int c = 0; c < 4; ++c) {
      const int j = wave * 4 + c;
      const int row = j * 8 + (lane >> 3);
      const int srcg = (lane & 7) ^ (row & 7);  // swizzle via source address
      async16(A + (size_t)(m0 + row) * KD + kt + srcg * 8, &sA[j * 512]);
      async16(BT + (size_t)(n0 + row) * KD + kt + srcg * 8, &sB[j * 512]);
    }
    __syncthreads();
#pragma unroll
    for (int ks = 0; ks < 2; ++ks) {
      half8 af[4], bf[4];
#pragma unroll
      for (int i = 0; i < 4; ++i) {
        const int ra = mw + i * 16 + l16;
        const int rb = nw + i * 16 + l16;
        af[i] = *(const half8*)&sA[ra * 64 + (((ks * 4 + quad) ^ (ra & 7)) * 8)];
        bf[i] = *(const half8*)&sB[rb * 64 + (((ks * 4 + quad) ^ (rb & 7)) * 8)];
      }
#pragma unroll
      for (int i = 0; i < 4; ++i)
#pragma unroll
        for (int j2 = 0; j2 < 4; ++j2)
          acc[i][j2] = MFMA(af[i], bf[j2], acc[i][j2]);
    }
    __syncthreads();
  }

  // epilogue: C row = (quad*4+reg), col = l16  [m89-verified]
#pragma unroll
  for (int i = 0; i < 4; ++i) {
#pragma unroll
    for (int j2 = 0; j2 < 4; ++j2) {
      const int col = n0 + nw + j2 * 16 + l16;
      const float bv = bias[col];
      const int rowb = m0 + mw + i * 16 + quad * 4;
#pragma unroll
      for (int r = 0; r < 4; ++r) {
        const float v = acc[i][j2][r] + bv;
        const int mrow = rowb + r;
        if (MODE == 0) {
          const int which = col / 1280;
          const int rem = col - which * 1280;
          const int h = rem / 80;
          const int kk = rem - h * 80;
          const int s = mrow >> 9, l = mrow & 511;
          const int shh = s * 16 + h;
          if (which == 0)
            Qf[((size_t)shh * 512 + l) * 96 + kk] = (_Float16)v;
          else if (which == 1)
            Kf[((size_t)shh * 512 + l) * 96 + kk] = (_Float16)v;
          else
            VTf[((size_t)shh * 80 + kk) * 512 + l] = (_Float16)v;
        } else {
          Out[(size_t)mrow * 1280 + col] = v;
        }
      }
    }
  }
}

// ---------------- RoPE in-place on Qf/Kf + zero the k-pad [80,96) -------------
__global__ __launch_bounds__(256) void rope_k(_Float16* __restrict__ Qf,
                                              _Float16* __restrict__ Kf,
                                              const float* __restrict__ cosNK,
                                              const float* __restrict__ sinNK) {
  const int gid = blockIdx.x * 256 + threadIdx.x;
  const int j = gid & 63;
  const int row = gid >> 6;
  const int qk = row >> 17;
  const int r = row & 131071;      // (s*16+h)*512 + l
  _Float16* buf = qk ? Kf : Qf;
  const int l = r & 511;
  const int s = r >> 13;
  const int t = s * 512 + l;
  const size_t base = (size_t)r * 96;
  if (j < 40) {
    const float v1 = (float)buf[base + j];
    const float v2 = (float)buf[base + j + 40];
    const float c1 = cosNK[t * 80 + j], s1 = sinNK[t * 80 + j];
    const float c2 = cosNK[t * 80 + j + 40], s2 = sinNK[t * 80 + j + 40];
    buf[base + j] = (_Float16)(v1 * c1 - v2 * s1);
    buf[base + j + 40] = (_Float16)(v2 * c2 + v1 * s2);
  } else if (j < 56) {
    buf[base + 40 + j] = (_Float16)0.f;  // kk = 80..95
  }
}

// ---------------- flash attention, no-max softmax, sum via ones-rows in V -----
// block = (seg-head, 128-row q tile). BR=128, BC=64, head dim 80 (pad 96).
__global__ __launch_bounds__(256) void attn_k(const _Float16* __restrict__ Qf,
                                              const _Float16* __restrict__ Kf,
                                              const _Float16* __restrict__ VTf,
                                              _Float16* __restrict__ attnA) {
  __shared__ _Float16 sQP[128 * 96];  // Q tile; later P tile (stride 72)
  __shared__ _Float16 sK[64 * 96];
  __shared__ _Float16 sV[96 * 72];    // rows 0..79: V^T tile; rows 80..95: ones
  const int tid = threadIdx.x;
  const int wave = tid >> 6, lane = tid & 63;
  const int quad = lane >> 4, l16 = lane & 15;
  const int shh = blockIdx.x;  // s*16+h
  const int qt = blockIdx.y;   // 0..3
  const int h = shh & 15;
  const int s = shh >> 4;

  const _Float16* Qb = Qf + ((size_t)shh * 512 + qt * 128) * 96;
  const _Float16* Kb0 = Kf + (size_t)shh * 512 * 96;
  const _Float16* Vb0 = VTf + (size_t)shh * 80 * 512;

  // stage Q (24 KB = 24 chunks)
#pragma unroll
  for (int c = 0; c < 6; ++c) {
    const int j = wave + 4 * c;
    async16(Qb + j * 512 + lane * 8, &sQP[j * 512]);
  }
  // ones rows for the row-sum trick (never touched by the masked V DMA)
  for (int idx = tid; idx < 16 * 72; idx += 256) sV[80 * 72 + idx] = (_Float16)1.f;
  __syncthreads();

  // hoist Q A-frags, pre-scaled by SCALE*log2e (base-2 softmax domain)
  const _Float16 c1h = (_Float16)(ATT_SCALE * LOG2E);
  half8 qf[2][3];
#pragma unroll
  for (int rt = 0; rt < 2; ++rt)
#pragma unroll
    for (int ks = 0; ks < 3; ++ks) {
      half8 t = *(const half8*)&sQP[(wave * 32 + rt * 16 + l16) * 96 + ks * 32 + quad * 8];
#pragma unroll
      for (int e = 0; e < 8; ++e) t[e] *= c1h;
      qf[rt][ks] = t;
    }

  f32x4 o[2][6] = {};  // ft 0..4: output features; ft 5: row sum

  for (int kc = 0; kc < 8; ++kc) {
    __syncthreads();  // prev iter LDS reads done (iter 0: hoist done)
    const _Float16* Kb = Kb0 + (size_t)kc * 64 * 96;
#pragma unroll
    for (int c = 0; c < 3; ++c) {
      const int j = wave + 4 * c;
      async16(Kb + j * 512 + lane * 8, &sK[j * 512]);
    }
    // VT tile into padded layout (row stride 72 halves = 144B), masked DMA
#pragma unroll
    for (int c = 0; c < 3; ++c) {
      const int j = wave + 4 * c;
      const int off = j * 1024 + lane * 16;  // LDS byte offset
      const int vrow = off / 144;
      const int colb = off - vrow * 144;
      if (vrow < 80 && colb < 128)
        async16(Vb0 + (size_t)vrow * 512 + kc * 64 + (colb >> 1), &sV[j * 512]);
    }
    __syncthreads();

    // S = (Q*C1) K^T  (fp32 acc, already in base-2 domain)
    f32x4 sacc[2][4] = {};
#pragma unroll
    for (int nt = 0; nt < 4; ++nt) {
#pragma unroll
      for (int ks = 0; ks < 3; ++ks) {
        half8 kb = *(const half8*)&sK[(nt * 16 + l16) * 96 + ks * 32 + quad * 8];
        sacc[0][nt] = MFMA(qf[0][ks], kb, sacc[0][nt]);
        sacc[1][nt] = MFMA(qf[1][ks], kb, sacc[1][nt]);
      }
    }

    // p = exp2(s) straight to LDS A-layout (rows are wave-private: no barrier)
    _Float16* sP = sQP;
#pragma unroll
    for (int rt = 0; rt < 2; ++rt)
#pragma unroll
      for (int nt = 0; nt < 4; ++nt)
#pragma unroll
        for (int r = 0; r < 4; ++r)
          sP[(wave * 32 + rt * 16 + quad * 4 + r) * 72 + nt * 16 + l16] =
              (_Float16)__builtin_amdgcn_exp2f(sacc[rt][nt][r]);

    // O += P V  (ft=5 accumulates the row sum via the ones rows)
#pragma unroll
    for (int ks = 0; ks < 2; ++ks) {
      half8 pa[2];
      pa[0] = *(const half8*)&sP[(wave * 32 + 0 + l16) * 72 + ks * 32 + quad * 8];
      pa[1] = *(const half8*)&sP[(wave * 32 + 16 + l16) * 72 + ks * 32 + quad * 8];
#pragma unroll
      for (int ft = 0; ft < 6; ++ft) {
        half8 vb = *(const half8*)&sV[(ft * 16 + l16) * 72 + ks * 32 + quad * 8];
        o[0][ft] = MFMA(pa[0], vb, o[0][ft]);
        o[1][ft] = MFMA(pa[1], vb, o[1][ft]);
      }
    }
  }

  // epilogue: divide by row sum, store fp16 into attnA [token][h*80+f]
#pragma unroll
  for (int rt = 0; rt < 2; ++rt) {
#pragma unroll
    for (int r = 0; r < 4; ++r) {
      const float inv = 1.0f / o[rt][5][r];
      const int token = s * 512 + qt * 128 + wave * 32 + rt * 16 + quad * 4 + r;
#pragma unroll
      for (int ft = 0; ft < 5; ++ft)
        attnA[(size_t)token * 1280 + h * 80 + ft * 16 + l16] =
            (_Float16)(o[rt][ft][r] * inv);
    }
  }
}

extern "C" void kernel_launch(void* const* d_in, const int* in_sizes, int n_in,
                              void* d_out, int out_size, void* d_ws, size_t ws_size,
                              hipStream_t stream) {
  (void)in_sizes; (void)n_in; (void)out_size; (void)ws_size;
  const float* hidden = (const float*)d_in[0];
  const float* cosNK = (const float*)d_in[2];
  const float* sinNK = (const float*)d_in[3];
  const float* qkv_w = (const float*)d_in[4];
  const float* qkv_b = (const float*)d_in[5];
  const float* proj_w = (const float*)d_in[6];
  const float* proj_b = (const float*)d_in[7];
  float* out = (float*)d_out;

  char* ws = (char*)d_ws;
  _Float16* hA    = (_Float16*)(ws);                   // 8192x1280        20971520 B
  _Float16* wT    = (_Float16*)(ws + 20971520);        // 3840x1280         9830400 B
  _Float16* projT = (_Float16*)(ws + 30801920);        // 1280x1280         3276800 B
  _Float16* Qf    = (_Float16*)(ws + 34078720);        // 256x512x96       25165824 B
  _Float16* Kf    = (_Float16*)(ws + 59244544);        // 256x512x96       25165824 B
  _Float16* VTf   = (_Float16*)(ws + 84410368);        // 256x80x512       20971520 B
  _Float16* attnA = (_Float16*)(ws + 105381888);       // 8192x1280        20971520 B

  cvt_k<<<10240, 256, 0, stream>>>(hidden, hA, 2621440);
  transpose_cvt_k<<<dim3(120, 40), 256, 0, stream>>>(qkv_w, wT, 1280, 3840);
  transpose_cvt_k<<<dim3(40, 40), 256, 0, stream>>>(proj_w, projT, 1280, 1280);
  gemm_k<0><<<dim3(64, 30), 256, 0, stream>>>(hA, wT, qkv_b, Qf, Kf, VTf, nullptr);
  rope_k<<<65536, 256, 0, stream>>>(Qf, Kf, cosNK, sinNK);
  attn_k<<<dim3(256, 4), 256, 0, stream>>>(Qf, Kf, VTf, attnA);
  gemm_k<1><<<dim3(64, 10), 256, 0, stream>>>(attnA, projT, proj_b, nullptr, nullptr,
                                              nullptr, out);
}

// Round 4
// 372.185 us; speedup vs baseline: 1.0952x; 1.0475x over previous
//
#include <hip/hip_runtime.h>

// Problem constants (fixed shape)
// N=8192 tokens, D=1280, H=16 heads, K=80 head dim (pad 96), S=16 segs, L=512
#define LOG2E 1.44269504088896340736f
#define ATT_SCALE 0.11180339887498949f  // 80^-0.5

typedef _Float16 half8 __attribute__((ext_vector_type(8)));
typedef _Float16 half4v __attribute__((ext_vector_type(4)));
typedef __fp16 fp16x2 __attribute__((ext_vector_type(2)));
typedef float f32x4 __attribute__((ext_vector_type(4)));

#define MFMA(a, b, c) __builtin_amdgcn_mfma_f32_16x16x32_f16((a), (b), (c), 0, 0, 0)

__device__ __forceinline__ void async16(const _Float16* g, _Float16* l) {
  __builtin_amdgcn_global_load_lds(
      (const __attribute__((address_space(1))) unsigned int*)g,
      (__attribute__((address_space(3))) unsigned int*)l,
      16, 0, 0);
}

// ---------------- fp32 -> fp16 convert (hidden) ----------------
__global__ __launch_bounds__(256) void cvt_k(const float* __restrict__ in,
                                             _Float16* __restrict__ out, int n4) {
  int i = blockIdx.x * 256 + threadIdx.x;
  if (i < n4) {
    f32x4 v = ((const f32x4*)in)[i];
    half4v hv;
    hv[0] = (_Float16)v[0]; hv[1] = (_Float16)v[1];
    hv[2] = (_Float16)v[2]; hv[3] = (_Float16)v[3];
    ((half4v*)out)[i] = hv;
  }
}

// ---------------- transpose + convert: in R x C fp32 -> out C x R fp16 ----------
__global__ __launch_bounds__(256) void transpose_cvt_k(const float* __restrict__ in,
                                                       _Float16* __restrict__ out,
                                                       int R, int C) {
  __shared__ float tile[32][33];
  const int tx = threadIdx.x & 31, ty = threadIdx.x >> 5;
  const int c0 = blockIdx.x * 32, r0 = blockIdx.y * 32;
#pragma unroll
  for (int i = 0; i < 32; i += 8)
    tile[ty + i][tx] = in[(size_t)(r0 + ty + i) * C + c0 + tx];
  __syncthreads();
#pragma unroll
  for (int i = 0; i < 32; i += 8)
    out[(size_t)(c0 + ty + i) * R + r0 + tx] = (_Float16)tile[tx][ty + i];
}

// ---------------- GEMM: C = A(8192xKd) * BT^T, Kd=1280, BK=32 ----------------
// LDS: row stride 32 halves; 8-half col-group physical = logical ^ ((row>>1)&3)
// (swizzle applied in DMA source addr + loop-invariant read addr -> 0 VALU/iter)
// MODE 0: N=3840, scatter epilogue -> Qf/Kf (seg-head x 512 x 96), VTf (80 x 512)
// MODE 1: N=1280, Out fp32 = val + bias
template <int MODE>
__global__ __launch_bounds__(256) void gemm_k(const _Float16* __restrict__ A,
                                              const _Float16* __restrict__ BT,
                                              const float* __restrict__ bias,
                                              _Float16* __restrict__ Qf,
                                              _Float16* __restrict__ Kf,
                                              _Float16* __restrict__ VTf,
                                              float* __restrict__ Out) {
  __shared__ _Float16 sA[128 * 32];
  __shared__ _Float16 sB[128 * 32];
  const int tid = threadIdx.x;
  const int wave = tid >> 6, lane = tid & 63;
  const int quad = lane >> 4, l16 = lane & 15;
  const int m0 = blockIdx.x * 128;
  const int n0 = blockIdx.y * 128;
  const int mw = (wave & 1) * 64, nw = (wave >> 1) * 64;
  const int KD = 1280;

  // DMA source group swizzle: loop-invariant per lane
  const int srcg = (lane & 3) ^ ((lane >> 3) & 3);
  // fragment-read physical group: loop-invariant per lane
  const int rg = (quad ^ ((l16 >> 1) & 3)) * 8;

  f32x4 acc[4][4] = {};

  for (int kt = 0; kt < KD; kt += 32) {
#pragma unroll
    for (int c = 0; c < 2; ++c) {
      const int j = wave * 2 + c;
      const int row = j * 16 + (lane >> 2);
      async16(A + (size_t)(m0 + row) * KD + kt + srcg * 8, &sA[j * 512]);
      async16(BT + (size_t)(n0 + row) * KD + kt + srcg * 8, &sB[j * 512]);
    }
    __syncthreads();
    half8 af[4], bf[4];
#pragma unroll
    for (int i = 0; i < 4; ++i) {
      af[i] = *(const half8*)&sA[(mw + i * 16 + l16) * 32 + rg];
      bf[i] = *(const half8*)&sB[(nw + i * 16 + l16) * 32 + rg];
    }
#pragma unroll
    for (int i = 0; i < 4; ++i)
#pragma unroll
      for (int j2 = 0; j2 < 4; ++j2)
        acc[i][j2] = MFMA(af[i], bf[j2], acc[i][j2]);
    __syncthreads();
  }

  // epilogue: C row = (quad*4+reg), col = l16  [m89-verified]
#pragma unroll
  for (int i = 0; i < 4; ++i) {
#pragma unroll
    for (int j2 = 0; j2 < 4; ++j2) {
      const int col = n0 + nw + j2 * 16 + l16;
      const float bv = bias[col];
      const int rowb = m0 + mw + i * 16 + quad * 4;
#pragma unroll
      for (int r = 0; r < 4; ++r) {
        const float v = acc[i][j2][r] + bv;
        const int mrow = rowb + r;
        if (MODE == 0) {
          const int which = col / 1280;
          const int rem = col - which * 1280;
          const int h = rem / 80;
          const int kk = rem - h * 80;
          const int s = mrow >> 9, l = mrow & 511;
          const int shh = s * 16 + h;
          if (which == 0)
            Qf[((size_t)shh * 512 + l) * 96 + kk] = (_Float16)v;
          else if (which == 1)
            Kf[((size_t)shh * 512 + l) * 96 + kk] = (_Float16)v;
          else
            VTf[((size_t)shh * 80 + kk) * 512 + l] = (_Float16)v;
        } else {
          Out[(size_t)mrow * 1280 + col] = v;
        }
      }
    }
  }
}

// ---------------- RoPE in-place on Qf/Kf + zero the k-pad [80,96) -------------
__global__ __launch_bounds__(256) void rope_k(_Float16* __restrict__ Qf,
                                              _Float16* __restrict__ Kf,
                                              const float* __restrict__ cosNK,
                                              const float* __restrict__ sinNK) {
  const int gid = blockIdx.x * 256 + threadIdx.x;
  const int j = gid & 63;
  const int row = gid >> 6;
  const int qk = row >> 17;
  const int r = row & 131071;      // (s*16+h)*512 + l
  _Float16* buf = qk ? Kf : Qf;
  const int l = r & 511;
  const int s = r >> 13;
  const int t = s * 512 + l;
  const size_t base = (size_t)r * 96;
  if (j < 40) {
    const float v1 = (float)buf[base + j];
    const float v2 = (float)buf[base + j + 40];
    const float c1 = cosNK[t * 80 + j], s1 = sinNK[t * 80 + j];
    const float c2 = cosNK[t * 80 + j + 40], s2 = sinNK[t * 80 + j + 40];
    buf[base + j] = (_Float16)(v1 * c1 - v2 * s1);
    buf[base + j + 40] = (_Float16)(v2 * c2 + v1 * s2);
  } else if (j < 56) {
    buf[base + 40 + j] = (_Float16)0.f;  // kk = 80..95
  }
}

// ---------------- flash attention (S^T form, no-max softmax, sum via ones) ----
// block = (seg-head, 128-row q tile). BR=128, BC=64, head dim 80 (pad 96).
// Q frags loaded global->reg directly. P written as packed b64 (consecutive k).
__global__ __launch_bounds__(256) void attn_k(const _Float16* __restrict__ Qf,
                                              const _Float16* __restrict__ Kf,
                                              const _Float16* __restrict__ VTf,
                                              _Float16* __restrict__ attnA) {
  __shared__ _Float16 sP[128 * 72];   // P tile, row stride 72
  __shared__ _Float16 sK[64 * 104];   // K tile, row stride 104 (conflict-free)
  __shared__ _Float16 sV[96 * 72];    // rows 0..79: V^T tile; rows 80..95: ones
  const int tid = threadIdx.x;
  const int wave = tid >> 6, lane = tid & 63;
  const int quad = lane >> 4, l16 = lane & 15;
  const int shh = blockIdx.x;  // s*16+h
  const int qt = blockIdx.y;   // 0..3
  const int h = shh & 15;
  const int s = shh >> 4;

  const _Float16* Qb = Qf + ((size_t)shh * 512 + qt * 128) * 96;
  const _Float16* Kb0 = Kf + (size_t)shh * 512 * 96;
  const _Float16* Vb0 = VTf + (size_t)shh * 80 * 512;

  // Q fragments straight from global (rows are lane-exact), pre-scaled
  const _Float16 c1h = (_Float16)(ATT_SCALE * LOG2E);
  half8 qf[2][3];
#pragma unroll
  for (int rt = 0; rt < 2; ++rt)
#pragma unroll
    for (int ks = 0; ks < 3; ++ks) {
      half8 t = *(const half8*)(Qb + (size_t)(wave * 32 + rt * 16 + l16) * 96 +
                                ks * 32 + quad * 8);
#pragma unroll
      for (int e = 0; e < 8; ++e) t[e] *= c1h;
      qf[rt][ks] = t;
    }

  // ones rows for the row-sum trick
  for (int idx = tid; idx < 16 * 72; idx += 256) sV[80 * 72 + idx] = (_Float16)1.f;

  f32x4 o[2][6] = {};  // ft 0..4: output features; ft 5: row sum

  for (int kc = 0; kc < 8; ++kc) {
    __syncthreads();  // prev iter LDS reads done (iter0: ones visible)
    // K tile -> sK, padded stride 104 halves (208 B), masked DMA (13 chunks)
    const _Float16* Kb = Kb0 + (size_t)kc * 64 * 96;
#pragma unroll
    for (int c = 0; c < 4; ++c) {
      const int j = wave + 4 * c;
      if (j < 13) {
        const int off = j * 1024 + lane * 16;  // LDS byte offset
        const int krow = off / 208;
        const int kcol = off - krow * 208;     // bytes within padded row
        if (kcol < 192)
          async16(Kb + (size_t)krow * 96 + (kcol >> 1), &sK[j * 512]);
      }
    }
    // V^T tile -> sV, padded stride 72 halves (144 B), masked DMA (12 chunks)
#pragma unroll
    for (int c = 0; c < 3; ++c) {
      const int j = wave + 4 * c;
      const int off = j * 1024 + lane * 16;
      const int vrow = off / 144;
      const int colb = off - vrow * 144;
      if (vrow < 80 && colb < 128)
        async16(Vb0 + (size_t)vrow * 512 + kc * 64 + (colb >> 1), &sV[j * 512]);
    }
    __syncthreads();

    // S^T = K Q^T (operand swap): lane holds S[q=l16][k=mt*16+quad*4+r]
    f32x4 sacc[2][4] = {};  // [rt][mt]
#pragma unroll
    for (int mt = 0; mt < 4; ++mt) {
#pragma unroll
      for (int ks = 0; ks < 3; ++ks) {
        half8 kb = *(const half8*)&sK[(mt * 16 + l16) * 104 + ks * 32 + quad * 8];
        sacc[0][mt] = MFMA(kb, qf[0][ks], sacc[0][mt]);
        sacc[1][mt] = MFMA(kb, qf[1][ks], sacc[1][mt]);
      }
    }

    // p = exp2(s), packed pairs (consecutive k!), one b64 store per (rt,mt)
#pragma unroll
    for (int rt = 0; rt < 2; ++rt) {
#pragma unroll
      for (int mt = 0; mt < 4; ++mt) {
        union { fp16x2 h2[2]; half4v h4; } u;
        u.h2[0] = __builtin_amdgcn_cvt_pkrtz(
            __builtin_amdgcn_exp2f(sacc[rt][mt][0]),
            __builtin_amdgcn_exp2f(sacc[rt][mt][1]));
        u.h2[1] = __builtin_amdgcn_cvt_pkrtz(
            __builtin_amdgcn_exp2f(sacc[rt][mt][2]),
            __builtin_amdgcn_exp2f(sacc[rt][mt][3]));
        *(half4v*)&sP[(wave * 32 + rt * 16 + l16) * 72 + mt * 16 + quad * 4] = u.h4;
      }
    }
    // sP rows are wave-private: per-wave LDS ordering suffices, no barrier

    // O += P V  (ft=5 accumulates the row sum via the ones rows)
#pragma unroll
    for (int ks = 0; ks < 2; ++ks) {
      half8 pa[2];
      pa[0] = *(const half8*)&sP[(wave * 32 + 0 + l16) * 72 + ks * 32 + quad * 8];
      pa[1] = *(const half8*)&sP[(wave * 32 + 16 + l16) * 72 + ks * 32 + quad * 8];
#pragma unroll
      for (int ft = 0; ft < 6; ++ft) {
        half8 vb = *(const half8*)&sV[(ft * 16 + l16) * 72 + ks * 32 + quad * 8];
        o[0][ft] = MFMA(pa[0], vb, o[0][ft]);
        o[1][ft] = MFMA(pa[1], vb, o[1][ft]);
      }
    }
  }

  // epilogue: divide by row sum, store fp16 into attnA [token][h*80+f]
#pragma unroll
  for (int rt = 0; rt < 2; ++rt) {
#pragma unroll
    for (int r = 0; r < 4; ++r) {
      const float inv = 1.0f / o[rt][5][r];
      const int token = s * 512 + qt * 128 + wave * 32 + rt * 16 + quad * 4 + r;
#pragma unroll
      for (int ft = 0; ft < 5; ++ft)
        attnA[(size_t)token * 1280 + h * 80 + ft * 16 + l16] =
            (_Float16)(o[rt][ft][r] * inv);
    }
  }
}

extern "C" void kernel_launch(void* const* d_in, const int* in_sizes, int n_in,
                              void* d_out, int out_size, void* d_ws, size_t ws_size,
                              hipStream_t stream) {
  (void)in_sizes; (void)n_in; (void)out_size; (void)ws_size;
  const float* hidden = (const float*)d_in[0];
  const float* cosNK = (const float*)d_in[2];
  const float* sinNK = (const float*)d_in[3];
  const float* qkv_w = (const float*)d_in[4];
  const float* qkv_b = (const float*)d_in[5];
  const float* proj_w = (const float*)d_in[6];
  const float* proj_b = (const float*)d_in[7];
  float* out = (float*)d_out;

  char* ws = (char*)d_ws;
  _Float16* hA    = (_Float16*)(ws);                   // 8192x1280        20971520 B
  _Float16* wT    = (_Float16*)(ws + 20971520);        // 3840x1280         9830400 B
  _Float16* projT = (_Float16*)(ws + 30801920);        // 1280x1280         3276800 B
  _Float16* Qf    = (_Float16*)(ws + 34078720);        // 256x512x96       25165824 B
  _Float16* Kf    = (_Float16*)(ws + 59244544);        // 256x512x96       25165824 B
  _Float16* VTf   = (_Float16*)(ws + 84410368);        // 256x80x512       20971520 B
  _Float16* attnA = (_Float16*)(ws + 105381888);       // 8192x1280        20971520 B

  cvt_k<<<10240, 256, 0, stream>>>(hidden, hA, 2621440);
  transpose_cvt_k<<<dim3(120, 40), 256, 0, stream>>>(qkv_w, wT, 1280, 3840);
  transpose_cvt_k<<<dim3(40, 40), 256, 0, stream>>>(proj_w, projT, 1280, 1280);
  gemm_k<0><<<dim3(64, 30), 256, 0, stream>>>(hA, wT, qkv_b, Qf, Kf, VTf, nullptr);
  rope_k<<<65536, 256, 0, stream>>>(Qf, Kf, cosNK, sinNK);
  attn_k<<<dim3(256, 4), 256, 0, stream>>>(Qf, Kf, VTf, attnA);
  gemm_k<1><<<dim3(64, 10), 256, 0, stream>>>(attnA, projT, proj_b, nullptr, nullptr,
                                              nullptr, out);
}

// Round 5
// 365.554 us; speedup vs baseline: 1.1151x; 1.0181x over previous
//
#include <hip/hip_runtime.h>

// Problem constants (fixed shape)
// N=8192 tokens, D=1280, H=16 heads, K=80 head dim (pad 96), S=16 segs, L=512
#define LOG2E 1.44269504088896340736f
#define ATT_SCALE 0.11180339887498949f  // 80^-0.5

typedef _Float16 half8 __attribute__((ext_vector_type(8)));
typedef _Float16 half4v __attribute__((ext_vector_type(4)));
typedef __fp16 fp16x2 __attribute__((ext_vector_type(2)));
typedef float f32x4 __attribute__((ext_vector_type(4)));

#define MFMA(a, b, c) __builtin_amdgcn_mfma_f32_16x16x32_f16((a), (b), (c), 0, 0, 0)

__device__ __forceinline__ void async16(const _Float16* g, _Float16* l) {
  __builtin_amdgcn_global_load_lds(
      (const __attribute__((address_space(1))) unsigned int*)g,
      (__attribute__((address_space(3))) unsigned int*)l,
      16, 0, 0);
}

// ---------------- fp32 -> fp16 convert (hidden) ----------------
__global__ __launch_bounds__(256) void cvt_k(const float* __restrict__ in,
                                             _Float16* __restrict__ out, int n4) {
  int i = blockIdx.x * 256 + threadIdx.x;
  if (i < n4) {
    f32x4 v = ((const f32x4*)in)[i];
    half4v hv;
    hv[0] = (_Float16)v[0]; hv[1] = (_Float16)v[1];
    hv[2] = (_Float16)v[2]; hv[3] = (_Float16)v[3];
    ((half4v*)out)[i] = hv;
  }
}

// ---------------- transpose + convert: in R x C fp32 -> out C x R fp16 ----------
__global__ __launch_bounds__(256) void transpose_cvt_k(const float* __restrict__ in,
                                                       _Float16* __restrict__ out,
                                                       int R, int C) {
  __shared__ float tile[32][33];
  const int tx = threadIdx.x & 31, ty = threadIdx.x >> 5;
  const int c0 = blockIdx.x * 32, r0 = blockIdx.y * 32;
#pragma unroll
  for (int i = 0; i < 32; i += 8)
    tile[ty + i][tx] = in[(size_t)(r0 + ty + i) * C + c0 + tx];
  __syncthreads();
#pragma unroll
  for (int i = 0; i < 32; i += 8)
    out[(size_t)(c0 + ty + i) * R + r0 + tx] = (_Float16)tile[tx][ty + i];
}

// ---------------- GEMM0: 256x128 tile, BK=32, swizzled LDS -------------------
// C = A(8192x1280) * BT^T (3840x1280), scatter epilogue -> Qf/Kf/VTf
// 32 MFMA per wave per K-iter (2x the 128-tile version): amortizes the
// vmcnt(0)+barrier drain that capped the 128-tile at 23% MfmaUtil.
__global__ __launch_bounds__(256, 2) void gemm256_k(const _Float16* __restrict__ A,
                                                    const _Float16* __restrict__ BT,
                                                    const float* __restrict__ bias,
                                                    _Float16* __restrict__ Qf,
                                                    _Float16* __restrict__ Kf,
                                                    _Float16* __restrict__ VTf) {
  __shared__ _Float16 sA[256 * 32];  // 16 KB
  __shared__ _Float16 sB[128 * 32];  // 8 KB
  const int tid = threadIdx.x;
  const int wave = tid >> 6, lane = tid & 63;
  const int quad = lane >> 4, l16 = lane & 15;
  const int m0 = blockIdx.x * 256;
  const int n0 = blockIdx.y * 128;
  const int mq = (wave & 1) * 128, nq = (wave >> 1) * 64;
  const int KD = 1280;

  // swizzle: physical 8-half group = logical ^ ((row>>1)&3); applied in DMA src
  const int srcg = (lane & 3) ^ ((lane >> 3) & 3);
  const int rg = (quad ^ ((l16 >> 1) & 3)) * 8;  // loop-invariant read group

  f32x4 acc[8][4] = {};

  for (int kt = 0; kt < KD; kt += 32) {
    // A: 16 chunks of 1KB (wave stages 4); B: 8 chunks (wave stages 2)
#pragma unroll
    for (int c = 0; c < 4; ++c) {
      const int j = wave * 4 + c;
      const int row = j * 16 + (lane >> 2);
      async16(A + (size_t)(m0 + row) * KD + kt + srcg * 8, &sA[j * 512]);
    }
#pragma unroll
    for (int c = 0; c < 2; ++c) {
      const int j = wave * 2 + c;
      const int row = j * 16 + (lane >> 2);
      async16(BT + (size_t)(n0 + row) * KD + kt + srcg * 8, &sB[j * 512]);
    }
    __syncthreads();
    half8 af[8], bf[4];
#pragma unroll
    for (int i = 0; i < 8; ++i)
      af[i] = *(const half8*)&sA[(mq + i * 16 + l16) * 32 + rg];
#pragma unroll
    for (int j = 0; j < 4; ++j)
      bf[j] = *(const half8*)&sB[(nq + j * 16 + l16) * 32 + rg];
#pragma unroll
    for (int i = 0; i < 8; ++i)
#pragma unroll
      for (int j2 = 0; j2 < 4; ++j2)
        acc[i][j2] = MFMA(af[i], bf[j2], acc[i][j2]);
    __syncthreads();
  }

  // scatter epilogue: C row = (quad*4+reg), col = l16  [m89-verified]
#pragma unroll
  for (int i = 0; i < 8; ++i) {
#pragma unroll
    for (int j2 = 0; j2 < 4; ++j2) {
      const int col = n0 + nq + j2 * 16 + l16;
      const float bv = bias[col];
      const int rowb = m0 + mq + i * 16 + quad * 4;
      const int which = col / 1280;
      const int rem = col - which * 1280;
      const int h = rem / 80;
      const int kk = rem - h * 80;
#pragma unroll
      for (int r = 0; r < 4; ++r) {
        const float v = acc[i][j2][r] + bv;
        const int mrow = rowb + r;
        const int s = mrow >> 9, l = mrow & 511;
        const int shh = s * 16 + h;
        if (which == 0)
          Qf[((size_t)shh * 512 + l) * 96 + kk] = (_Float16)v;
        else if (which == 1)
          Kf[((size_t)shh * 512 + l) * 96 + kk] = (_Float16)v;
        else
          VTf[((size_t)shh * 80 + kk) * 512 + l] = (_Float16)v;
      }
    }
  }
}

// ---------------- GEMM1: 128x128 tile (proj): Out fp32 = A * projT^T + bias --
__global__ __launch_bounds__(256) void gemm_k(const _Float16* __restrict__ A,
                                              const _Float16* __restrict__ BT,
                                              const float* __restrict__ bias,
                                              float* __restrict__ Out) {
  __shared__ _Float16 sA[128 * 32];
  __shared__ _Float16 sB[128 * 32];
  const int tid = threadIdx.x;
  const int wave = tid >> 6, lane = tid & 63;
  const int quad = lane >> 4, l16 = lane & 15;
  const int m0 = blockIdx.x * 128;
  const int n0 = blockIdx.y * 128;
  const int mw = (wave & 1) * 64, nw = (wave >> 1) * 64;
  const int KD = 1280;

  const int srcg = (lane & 3) ^ ((lane >> 3) & 3);
  const int rg = (quad ^ ((l16 >> 1) & 3)) * 8;

  f32x4 acc[4][4] = {};

  for (int kt = 0; kt < KD; kt += 32) {
#pragma unroll
    for (int c = 0; c < 2; ++c) {
      const int j = wave * 2 + c;
      const int row = j * 16 + (lane >> 2);
      async16(A + (size_t)(m0 + row) * KD + kt + srcg * 8, &sA[j * 512]);
      async16(BT + (size_t)(n0 + row) * KD + kt + srcg * 8, &sB[j * 512]);
    }
    __syncthreads();
    half8 af[4], bf[4];
#pragma unroll
    for (int i = 0; i < 4; ++i) {
      af[i] = *(const half8*)&sA[(mw + i * 16 + l16) * 32 + rg];
      bf[i] = *(const half8*)&sB[(nw + i * 16 + l16) * 32 + rg];
    }
#pragma unroll
    for (int i = 0; i < 4; ++i)
#pragma unroll
      for (int j2 = 0; j2 < 4; ++j2)
        acc[i][j2] = MFMA(af[i], bf[j2], acc[i][j2]);
    __syncthreads();
  }

#pragma unroll
  for (int i = 0; i < 4; ++i) {
#pragma unroll
    for (int j2 = 0; j2 < 4; ++j2) {
      const int col = n0 + nw + j2 * 16 + l16;
      const float bv = bias[col];
      const int rowb = m0 + mw + i * 16 + quad * 4;
#pragma unroll
      for (int r = 0; r < 4; ++r)
        Out[(size_t)(rowb + r) * 1280 + col] = acc[i][j2][r] + bv;
    }
  }
}

// ---------------- RoPE in-place on Qf/Kf + zero the k-pad [80,96) -------------
__global__ __launch_bounds__(256) void rope_k(_Float16* __restrict__ Qf,
                                              _Float16* __restrict__ Kf,
                                              const float* __restrict__ cosNK,
                                              const float* __restrict__ sinNK) {
  const int gid = blockIdx.x * 256 + threadIdx.x;
  const int j = gid & 63;
  const int row = gid >> 6;
  const int qk = row >> 17;
  const int r = row & 131071;      // (s*16+h)*512 + l
  _Float16* buf = qk ? Kf : Qf;
  const int l = r & 511;
  const int s = r >> 13;
  const int t = s * 512 + l;
  const size_t base = (size_t)r * 96;
  if (j < 40) {
    const float v1 = (float)buf[base + j];
    const float v2 = (float)buf[base + j + 40];
    const float c1 = cosNK[t * 80 + j], s1 = sinNK[t * 80 + j];
    const float c2 = cosNK[t * 80 + j + 40], s2 = sinNK[t * 80 + j + 40];
    buf[base + j] = (_Float16)(v1 * c1 - v2 * s1);
    buf[base + j + 40] = (_Float16)(v2 * c2 + v1 * s2);
  } else if (j < 56) {
    buf[base + 40 + j] = (_Float16)0.f;  // kk = 80..95
  }
}

// ---------------- flash attention (S^T form, no-max softmax, sum via ones) ----
__global__ __launch_bounds__(256) void attn_k(const _Float16* __restrict__ Qf,
                                              const _Float16* __restrict__ Kf,
                                              const _Float16* __restrict__ VTf,
                                              _Float16* __restrict__ attnA) {
  __shared__ _Float16 sP[128 * 72];   // P tile, row stride 72
  __shared__ _Float16 sK[64 * 104];   // K tile, row stride 104 (conflict-free)
  __shared__ _Float16 sV[96 * 72];    // rows 0..79: V^T tile; rows 80..95: ones
  const int tid = threadIdx.x;
  const int wave = tid >> 6, lane = tid & 63;
  const int quad = lane >> 4, l16 = lane & 15;
  const int shh = blockIdx.x;  // s*16+h
  const int qt = blockIdx.y;   // 0..3
  const int h = shh & 15;
  const int s = shh >> 4;

  const _Float16* Qb = Qf + ((size_t)shh * 512 + qt * 128) * 96;
  const _Float16* Kb0 = Kf + (size_t)shh * 512 * 96;
  const _Float16* Vb0 = VTf + (size_t)shh * 80 * 512;

  // Q fragments straight from global (rows are lane-exact), pre-scaled
  const _Float16 c1h = (_Float16)(ATT_SCALE * LOG2E);
  half8 qf[2][3];
#pragma unroll
  for (int rt = 0; rt < 2; ++rt)
#pragma unroll
    for (int ks = 0; ks < 3; ++ks) {
      half8 t = *(const half8*)(Qb + (size_t)(wave * 32 + rt * 16 + l16) * 96 +
                                ks * 32 + quad * 8);
#pragma unroll
      for (int e = 0; e < 8; ++e) t[e] *= c1h;
      qf[rt][ks] = t;
    }

  // ones rows for the row-sum trick
  for (int idx = tid; idx < 16 * 72; idx += 256) sV[80 * 72 + idx] = (_Float16)1.f;

  f32x4 o[2][6] = {};  // ft 0..4: output features; ft 5: row sum

  for (int kc = 0; kc < 8; ++kc) {
    __syncthreads();  // prev iter LDS reads done (iter0: ones visible)
    // K tile -> sK, padded stride 104 halves (208 B), masked DMA (13 chunks)
    const _Float16* Kb = Kb0 + (size_t)kc * 64 * 96;
#pragma unroll
    for (int c = 0; c < 4; ++c) {
      const int j = wave + 4 * c;
      if (j < 13) {
        const int off = j * 1024 + lane * 16;  // LDS byte offset
        const int krow = off / 208;
        const int kcol = off - krow * 208;     // bytes within padded row
        if (kcol < 192)
          async16(Kb + (size_t)krow * 96 + (kcol >> 1), &sK[j * 512]);
      }
    }
    // V^T tile -> sV, padded stride 72 halves (144 B), masked DMA (12 chunks)
#pragma unroll
    for (int c = 0; c < 3; ++c) {
      const int j = wave + 4 * c;
      const int off = j * 1024 + lane * 16;
      const int vrow = off / 144;
      const int colb = off - vrow * 144;
      if (vrow < 80 && colb < 128)
        async16(Vb0 + (size_t)vrow * 512 + kc * 64 + (colb >> 1), &sV[j * 512]);
    }
    __syncthreads();

    // S^T = K Q^T (operand swap): lane holds S[q=l16][k=mt*16+quad*4+r]
    f32x4 sacc[2][4] = {};  // [rt][mt]
#pragma unroll
    for (int mt = 0; mt < 4; ++mt) {
#pragma unroll
      for (int ks = 0; ks < 3; ++ks) {
        half8 kb = *(const half8*)&sK[(mt * 16 + l16) * 104 + ks * 32 + quad * 8];
        sacc[0][mt] = MFMA(kb, qf[0][ks], sacc[0][mt]);
        sacc[1][mt] = MFMA(kb, qf[1][ks], sacc[1][mt]);
      }
    }

    // p = exp2(s), packed pairs (consecutive k!), one b64 store per (rt,mt)
#pragma unroll
    for (int rt = 0; rt < 2; ++rt) {
#pragma unroll
      for (int mt = 0; mt < 4; ++mt) {
        union { fp16x2 h2[2]; half4v h4; } u;
        u.h2[0] = __builtin_amdgcn_cvt_pkrtz(
            __builtin_amdgcn_exp2f(sacc[rt][mt][0]),
            __builtin_amdgcn_exp2f(sacc[rt][mt][1]));
        u.h2[1] = __builtin_amdgcn_cvt_pkrtz(
            __builtin_amdgcn_exp2f(sacc[rt][mt][2]),
            __builtin_amdgcn_exp2f(sacc[rt][mt][3]));
        *(half4v*)&sP[(wave * 32 + rt * 16 + l16) * 72 + mt * 16 + quad * 4] = u.h4;
      }
    }
    // sP rows are wave-private: per-wave LDS ordering suffices, no barrier

    // O += P V  (ft=5 accumulates the row sum via the ones rows)
#pragma unroll
    for (int ks = 0; ks < 2; ++ks) {
      half8 pa[2];
      pa[0] = *(const half8*)&sP[(wave * 32 + 0 + l16) * 72 + ks * 32 + quad * 8];
      pa[1] = *(const half8*)&sP[(wave * 32 + 16 + l16) * 72 + ks * 32 + quad * 8];
#pragma unroll
      for (int ft = 0; ft < 6; ++ft) {
        half8 vb = *(const half8*)&sV[(ft * 16 + l16) * 72 + ks * 32 + quad * 8];
        o[0][ft] = MFMA(pa[0], vb, o[0][ft]);
        o[1][ft] = MFMA(pa[1], vb, o[1][ft]);
      }
    }
  }

  // epilogue: divide by row sum, store fp16 into attnA [token][h*80+f]
#pragma unroll
  for (int rt = 0; rt < 2; ++rt) {
#pragma unroll
    for (int r = 0; r < 4; ++r) {
      const float inv = 1.0f / o[rt][5][r];
      const int token = s * 512 + qt * 128 + wave * 32 + rt * 16 + quad * 4 + r;
#pragma unroll
      for (int ft = 0; ft < 5; ++ft)
        attnA[(size_t)token * 1280 + h * 80 + ft * 16 + l16] =
            (_Float16)(o[rt][ft][r] * inv);
    }
  }
}

extern "C" void kernel_launch(void* const* d_in, const int* in_sizes, int n_in,
                              void* d_out, int out_size, void* d_ws, size_t ws_size,
                              hipStream_t stream) {
  (void)in_sizes; (void)n_in; (void)out_size; (void)ws_size;
  const float* hidden = (const float*)d_in[0];
  const float* cosNK = (const float*)d_in[2];
  const float* sinNK = (const float*)d_in[3];
  const float* qkv_w = (const float*)d_in[4];
  const float* qkv_b = (const float*)d_in[5];
  const float* proj_w = (const float*)d_in[6];
  const float* proj_b = (const float*)d_in[7];
  float* out = (float*)d_out;

  char* ws = (char*)d_ws;
  _Float16* hA    = (_Float16*)(ws);                   // 8192x1280        20971520 B
  _Float16* wT    = (_Float16*)(ws + 20971520);        // 3840x1280         9830400 B
  _Float16* projT = (_Float16*)(ws + 30801920);        // 1280x1280         3276800 B
  _Float16* Qf    = (_Float16*)(ws + 34078720);        // 256x512x96       25165824 B
  _Float16* Kf    = (_Float16*)(ws + 59244544);        // 256x512x96       25165824 B
  _Float16* VTf   = (_Float16*)(ws + 84410368);        // 256x80x512       20971520 B
  _Float16* attnA = (_Float16*)(ws + 105381888);       // 8192x1280        20971520 B

  cvt_k<<<10240, 256, 0, stream>>>(hidden, hA, 2621440);
  transpose_cvt_k<<<dim3(120, 40), 256, 0, stream>>>(qkv_w, wT, 1280, 3840);
  transpose_cvt_k<<<dim3(40, 40), 256, 0, stream>>>(proj_w, projT, 1280, 1280);
  gemm256_k<<<dim3(32, 30), 256, 0, stream>>>(hA, wT, qkv_b, Qf, Kf, VTf);
  rope_k<<<65536, 256, 0, stream>>>(Qf, Kf, cosNK, sinNK);
  attn_k<<<dim3(256, 4), 256, 0, stream>>>(Qf, Kf, VTf, attnA);
  gemm_k<<<dim3(64, 10), 256, 0, stream>>>(attnA, projT, proj_b, out);
}